// Round 3
// baseline (212.855 us; speedup 1.0000x reference)
//
#include <hip/hip_runtime.h>
#include <cmath>

#define QN    65536
#define KVN   65536
#define CD    256
#define NH    8
#define NE    524288
#define SCL   0.0625f      // 1/sqrt(256)
#define LNEPS 1e-5f
#define LOG2E 1.4426950408889634f

typedef __bf16 bf16x8 __attribute__((ext_vector_type(8)));
typedef float  f32x4  __attribute__((ext_vector_type(4)));

__device__ __forceinline__ float b2f(ushort u) {
    return __builtin_bit_cast(float, (unsigned)u << 16);
}
__device__ __forceinline__ ushort f2bf(float f) {
    unsigned u = __builtin_bit_cast(unsigned, f);
    return (ushort)((u + 0x7FFFu + ((u >> 16) & 1u)) >> 16);   // RNE
}

#if __has_builtin(__builtin_amdgcn_exp2f)
__device__ __forceinline__ float fexp2(float x) { return __builtin_amdgcn_exp2f(x); }
#else
__device__ __forceinline__ float fexp2(float x) {
    float r; asm volatile("v_exp_f32 %0, %1" : "=v"(r) : "v"(x)); return r;
}
#endif

#define GLD16(g, l) __builtin_amdgcn_global_load_lds( \
    (const __attribute__((address_space(1))) unsigned int*)(const void*)(g), \
    (__attribute__((address_space(3))) unsigned int*)(void*)(l), 16, 0, 0)

// ---------------------------------------------------------------- fused prep:
// blk [0, LNB):          LN(q) -> bf16 qn           (4 rows/block)
// blk [LNB, LNB+192):    wq|wk|wo fp32 -> bf16      (1024 els/block)
// blk [.., +NE/256):     CSR row_lo fill
// blk [.., +LNB):        k fp32 -> bf16 kb          (4 rows/block)
#define LNB   (QN / 4)
#define RLB   (NE / 256)
__global__ __launch_bounds__(256) void prep_k(const float* __restrict__ q,
                                              const float* __restrict__ k,
                                              const float* __restrict__ lnw,
                                              const float* __restrict__ lnb,
                                              const float* __restrict__ wq,
                                              const float* __restrict__ wk,
                                              const float* __restrict__ wo,
                                              const int* __restrict__ dst,
                                              ushort* __restrict__ qn,
                                              ushort* __restrict__ kb,
                                              ushort* __restrict__ wb,
                                              int* __restrict__ row_lo) {
    const int blk = blockIdx.x;
    if (blk < LNB) {
        int row  = (blk << 2) + (threadIdx.x >> 6);
        int lane = threadIdx.x & 63;
        float4 v = *(const float4*)(q + (size_t)row * CD + (lane << 2));
        float s  = v.x + v.y + v.z + v.w;
        float s2 = v.x * v.x + v.y * v.y + v.z * v.z + v.w * v.w;
        #pragma unroll
        for (int m = 1; m < 64; m <<= 1) {
            s  += __shfl_xor(s, m);
            s2 += __shfl_xor(s2, m);
        }
        float mu   = s * (1.0f / CD);
        float rstd = rsqrtf(s2 * (1.0f / CD) - mu * mu + LNEPS);
        float4 w = *(const float4*)(lnw + (lane << 2));
        float4 b = *(const float4*)(lnb + (lane << 2));
        ushort4 o;
        o.x = f2bf((v.x - mu) * rstd * w.x + b.x);
        o.y = f2bf((v.y - mu) * rstd * w.y + b.y);
        o.z = f2bf((v.z - mu) * rstd * w.z + b.z);
        o.w = f2bf((v.w - mu) * rstd * w.w + b.w);
        *(ushort4*)(qn + (size_t)row * CD + (lane << 2)) = o;
    } else if (blk < LNB + 192) {
        int idx4 = ((blk - LNB) * 256 + threadIdx.x) * 4;   // 0 .. 3*65536
        int mat  = idx4 >> 16;
        int off  = idx4 & 65535;
        const float* src = (mat == 0) ? wq : (mat == 1) ? wk : wo;
        float4 v = *(const float4*)(src + off);
        ushort4 o;
        o.x = f2bf(v.x); o.y = f2bf(v.y); o.z = f2bf(v.z); o.w = f2bf(v.w);
        *(ushort4*)(wb + idx4) = o;
    } else if (blk < LNB + 192 + RLB) {
        int e = (blk - LNB - 192) * 256 + threadIdx.x;
        int d     = dst[e];
        int dprev = (e == 0) ? -1 : dst[e - 1];
        for (int qq = dprev + 1; qq <= d; ++qq) row_lo[qq] = e;
        if (e == NE - 1)
            for (int qq = d + 1; qq <= QN; ++qq) row_lo[qq] = NE;
    } else {
        int row  = ((blk - LNB - 192 - RLB) << 2) + (threadIdx.x >> 6);
        int lane = threadIdx.x & 63;
        float4 v = *(const float4*)(k + (size_t)row * CD + (lane << 2));
        ushort4 o;
        o.x = f2bf(v.x); o.y = f2bf(v.y); o.z = f2bf(v.z); o.w = f2bf(v.w);
        *(ushort4*)(kb + (size_t)row * CD + (lane << 2)) = o;
    }
}

// ---------------------------------------------------------------- persistent bf16 GEMM
// One block per CU (LDS 128 KB), 512 threads = 8 waves (2m x 4n), tile 128x128.
// B panel (256x128-col slice of the weight matrix, 64 KB) loaded into LDS ONCE.
// A streamed through an 8-slot LDS ring (8 KB/slot) with stage-ahead-6 and
// counted s_waitcnt vmcnt(N); ONE s_barrier per K-step.  NT row-tiles / block.
// Swapped MFMA operands (mfma(bg, af)) put 4 consecutive C-cols per lane ->
// vectorized epilogue stores that keep post-epilogue waits counted.
// EPI 0: bf16 out (E=8).  EPI 1: f32 out + resid (E=16).
template<int EPI, int NT>
__global__ __launch_bounds__(512) void gemm2_k(const ushort* __restrict__ A0,
                                               const ushort* __restrict__ A1,
                                               const ushort* __restrict__ B0,
                                               const ushort* __restrict__ B1,
                                               const float* __restrict__ bias0,
                                               const float* __restrict__ bias1,
                                               const float* __restrict__ resid,
                                               void* __restrict__ C0,
                                               void* __restrict__ C1) {
    const bool second = (blockIdx.z != 0);
    const ushort* Ap   = second ? A1 : A0;
    const ushort* B    = second ? B1 : B0;
    const float*  bias = second ? bias1 : bias0;
    void*         Cout = second ? C1 : C0;

    __shared__ __align__(16) ushort Bs[8][4096];   // 64 KB: full B panel, 8 k-slices
    __shared__ __align__(16) ushort As[8][4096];   // 64 KB: A ring, 8 slots

    const int t    = threadIdx.x;
    const int lane = t & 63;
    const int wid  = t >> 6;             // 0..7
    const int wm   = wid & 1;            // 2 wave-rows
    const int wn   = wid >> 1;           // 4 wave-cols
    const size_t bn  = (size_t)blockIdx.y * 128;
    size_t bm = (size_t)blockIdx.x * (NT * 128);

    const int sr = t >> 2;               // 0..127 staging row
    const int sc = (t & 3) * 8;          // staging col (8 ushorts = 16 B)

    constexpr int E = (EPI == 0) ? 8 : 16;   // epilogue vmem instrs (stores [+resid loads])

    f32x4 acc[4][2] = {};
    f32x4 biasv[2];
    #pragma unroll
    for (int ni = 0; ni < 2; ++ni)
        biasv[ni] = *(const f32x4*)(bias + bn + wn * 32 + ni * 16 + ((lane >> 4) << 2));

    // ---- prologue: whole B panel + A slots 0..5
    #pragma unroll
    for (int s = 0; s < 8; ++s)
        GLD16(B + (bn + sr) * CD + (s << 5) + sc, &Bs[s][wid << 9]);
    #pragma unroll
    for (int s = 0; s < 6; ++s)
        GLD16(Ap + (bm + sr) * CD + (s << 5) + sc, &As[s][wid << 9]);
    // materialize bias NOW (counted wait vmcnt(14), not a ring-drain at 1st epilogue)
    asm volatile("" : "+v"(biasv[0]), "+v"(biasv[1]));

    // KSTEP: stage slot (KT+6) [tile +1 when KT>=2], counted wait + barrier,
    // then 6 ds_read_b128 + 8 MFMA on slot KT.
#define KSTEP(KT, VM, GUARD)                                                          \
  {                                                                                   \
    if (GUARD) {                                                                      \
      const ushort* ga_ = Ap + (bm + (((KT) >= 2) ? 128 : 0) + sr) * CD               \
                          + ((((KT) + 6) & 7) << 5) + sc;                             \
      GLD16(ga_, &As[((KT) + 6) & 7][wid << 9]);                                      \
    }                                                                                 \
    asm volatile("s_waitcnt vmcnt(%0) lgkmcnt(0)\n\ts_barrier" :: "i"(VM) : "memory");\
    {                                                                                 \
      const int kq_ = (lane >> 4) << 3;                                               \
      bf16x8 af_[4], bg_[2];                                                          \
      _Pragma("unroll")                                                               \
      for (int mi = 0; mi < 4; ++mi)                                                  \
        af_[mi] = *(const bf16x8*)&As[(KT) & 7][((wm * 64 + mi * 16 + (lane & 15)) << 5) + kq_]; \
      _Pragma("unroll")                                                               \
      for (int ni = 0; ni < 2; ++ni)                                                  \
        bg_[ni] = *(const bf16x8*)&Bs[(KT)][((wn * 32 + ni * 16 + (lane & 15)) << 5) + kq_];     \
      _Pragma("unroll")                                                               \
      for (int mi = 0; mi < 4; ++mi)                                                  \
        _Pragma("unroll")                                                             \
        for (int ni = 0; ni < 2; ++ni)                                                \
          acc[mi][ni] = __builtin_amdgcn_mfma_f32_16x16x32_bf16(bg_[ni], af_[mi], acc[mi][ni], 0, 0, 0); \
    }                                                                                 \
  }

    // swapped-operand layout: lane holds row = ..+(lane&15), cols = ..+(lane>>4)*4+r
#define EPILOG()                                                                      \
  {                                                                                   \
    _Pragma("unroll")                                                                 \
    for (int mi = 0; mi < 4; ++mi) {                                                  \
      const size_t row_ = bm + wm * 64 + mi * 16 + (lane & 15);                       \
      _Pragma("unroll")                                                               \
      for (int ni = 0; ni < 2; ++ni) {                                                \
        const size_t col_ = bn + wn * 32 + ni * 16 + ((lane >> 4) << 2);              \
        if (EPI == 0) {                                                               \
          ushort4 o_;                                                                 \
          o_.x = f2bf(acc[mi][ni][0] + biasv[ni][0]);                                 \
          o_.y = f2bf(acc[mi][ni][1] + biasv[ni][1]);                                 \
          o_.z = f2bf(acc[mi][ni][2] + biasv[ni][2]);                                 \
          o_.w = f2bf(acc[mi][ni][3] + biasv[ni][3]);                                 \
          *(ushort4*)((ushort*)Cout + row_ * CD + col_) = o_;                         \
        } else {                                                                      \
          f32x4 rs_ = *(const f32x4*)(resid + row_ * CD + col_);                      \
          f32x4 o_;                                                                   \
          o_[0] = acc[mi][ni][0] + biasv[ni][0] + rs_[0];                             \
          o_[1] = acc[mi][ni][1] + biasv[ni][1] + rs_[1];                             \
          o_[2] = acc[mi][ni][2] + biasv[ni][2] + rs_[2];                             \
          o_[3] = acc[mi][ni][3] + biasv[ni][3] + rs_[3];                             \
          *(f32x4*)((float*)Cout + row_ * CD + col_) = o_;                            \
        }                                                                             \
        acc[mi][ni] = (f32x4){0.f, 0.f, 0.f, 0.f};                                    \
      }                                                                               \
    }                                                                                 \
    asm volatile("" ::: "memory");  /* keep stores before next tile's stage */        \
  }

    // ---- tile 0 (no prior stores in flight): steady vmcnt(6)
    KSTEP(0, 6, 1) KSTEP(1, 6, 1) KSTEP(2, 6, 1) KSTEP(3, 6, 1)
    KSTEP(4, 6, 1) KSTEP(5, 6, 1) KSTEP(6, 6, 1) KSTEP(7, 6, 1)
    EPILOG();
    bm += 128;

    // ---- middle tiles: previous epilogue's E stores sit between slot(t,5)
    // and slot(t,6) in vmcnt age order -> kt0..5 allow 6+E, kt6..7 back to 6.
    for (int tt = 1; tt < NT - 1; ++tt) {
        KSTEP(0, 6 + E, 1) KSTEP(1, 6 + E, 1) KSTEP(2, 6 + E, 1) KSTEP(3, 6 + E, 1)
        KSTEP(4, 6 + E, 1) KSTEP(5, 6 + E, 1) KSTEP(6, 6, 1)     KSTEP(7, 6, 1)
        EPILOG();
        bm += 128;
    }

    // ---- last tile: staging stops after kt1; tail counts shrink
    KSTEP(0, 6 + E, 1) KSTEP(1, 6 + E, 1) KSTEP(2, 5 + E, 0) KSTEP(3, 4 + E, 0)
    KSTEP(4, 3 + E, 0) KSTEP(5, 2 + E, 0) KSTEP(6, 1, 0)     KSTEP(7, 0, 0)
    EPILOG();

#undef KSTEP
#undef EPILOG
}

// ---------------------------------------------------------------- edge attention
// v3: 4 queries per block (1 wave each, no barriers) -> 16384 workgroups
// (was 65536: at 2.56 chip-cycles/WG the CP dispatch rate was the cap).
// Chunk-deferred online softmax: all 8 sims of a chunk computed into regs,
// ONE max+rescale per chunk, then 8 independent ex*kv FMA accumulations
// (removes the per-edge serial rescale chain).
__global__ __launch_bounds__(256) void edge_attn_k(const ushort* __restrict__ qp,
                                                   const ushort* __restrict__ kp,
                                                   const float* __restrict__ bias,
                                                   const int* __restrict__ src,
                                                   const int* __restrict__ row_lo,
                                                   ushort* __restrict__ ao,
                                                   float* __restrict__ simw) {
    const int q    = (blockIdx.x << 2) + (threadIdx.x >> 6);
    const int lane = threadIdx.x & 63;
    const int lo = row_lo[q];
    const int hi = row_lo[q + 1];
    const int deg = hi - lo;
    const float SC2 = SCL * LOG2E;

    ushort4 qu = *(const ushort4*)(qp + (size_t)q * CD + (lane << 2));
    float4 qv = {b2f(qu.x) * SC2, b2f(qu.y) * SC2, b2f(qu.z) * SC2, b2f(qu.w) * SC2};
    float4 acc = {0.f, 0.f, 0.f, 0.f};
    float m = -INFINITY, s = 0.f;
    float wval0 = 0.f, wval1 = 0.f;      // chunk-0 / chunk-1 transposed sims

    for (int base = lo; base < hi; base += 8) {
        const int cnum = (base - lo) >> 3;
        // ---- load phase: 1 src chunk + 1 bias chunk + up to 8 kp rows
        int sv = 0;
        if (lane < 8 && base + lane < hi) sv = src[base + lane];
        float bch = 0.f;
        if (lane < (hi - base) * 8) bch = bias[(size_t)base * NH + lane] * SC2;
        float4 kv[8];
        #pragma unroll
        for (int i = 0; i < 8; ++i) {
            if (base + i < hi) {
                int sidx = __shfl(sv, i);
                ushort4 ku = *(const ushort4*)(kp + (size_t)sidx * CD + (lane << 2));
                kv[i] = (float4){b2f(ku.x), b2f(ku.y), b2f(ku.z), b2f(ku.w)};
            }
        }
        // ---- sims for the whole chunk (independent across edges)
        float sims[8];
        #pragma unroll
        for (int i = 0; i < 8; ++i) sims[i] = -INFINITY;
        #pragma unroll
        for (int i = 0; i < 8; ++i) {
            if (base + i < hi) {
                float d = qv.x * kv[i].x + qv.y * kv[i].y + qv.z * kv[i].z + qv.w * kv[i].w;
                d += __shfl_xor(d, 1);
                d += __shfl_xor(d, 2);
                d += __shfl_xor(d, 4);
                float bvi = __shfl(bch, (i << 3) + (lane >> 3));
                float sim = d + bvi;                       // log2 domain
                sims[i] = sim;
                float tw = __shfl(sim, (lane & 7) << 3);   // capture for weights output
                bool mine = ((lane >> 3) == i);
                if (deg <= 16) {
                    if (cnum == 0) wval0 = mine ? tw : wval0;
                    else           wval1 = mine ? tw : wval1;
                } else {
                    wval0 = mine ? tw : wval0;             // rolling (staged per chunk)
                }
            }
        }
        // ---- one rescale per chunk, then independent accumulations
        float cmax = fmaxf(fmaxf(fmaxf(sims[0], sims[1]), fmaxf(sims[2], sims[3])),
                           fmaxf(fmaxf(sims[4], sims[5]), fmaxf(sims[6], sims[7])));
        float mnew  = fmaxf(m, cmax);
        float scale = fexp2(m - mnew);     // first chunk: exp2(-inf)=0
        s *= scale;
        acc.x *= scale; acc.y *= scale; acc.z *= scale; acc.w *= scale;
        #pragma unroll
        for (int i = 0; i < 8; ++i) {
            if (base + i < hi) {
                float ex = fexp2(sims[i] - mnew);
                s += ex;
                acc.x += ex * kv[i].x;
                acc.y += ex * kv[i].y;
                acc.z += ex * kv[i].z;
                acc.w += ex * kv[i].w;
            }
        }
        m = mnew;
        // ---- stage raw (log2) sims only for deg>16 queries (rare)
        if (deg > 16) {
            int lim = hi - base; if (lim > 8) lim = 8;
            if (lane < lim * 8) simw[(size_t)base * NH + lane] = wval0;
        }
    }

    float ws  = s + 1e-8f;
    float inv = 1.0f / ws;
    ushort4 o;
    o.x = f2bf(acc.x * inv);
    o.y = f2bf(acc.y * inv);
    o.z = f2bf(acc.z * inv);
    o.w = f2bf(acc.w * inv);
    *(ushort4*)(ao + (size_t)q * CD + (lane << 2)) = o;

    if (deg > 0) {
        const float mm = __shfl(m,   (lane & 7) << 3);     // state of head lane&7
        const float ii = __shfl(inv, (lane & 7) << 3);
        if (deg <= 8) {
            if (lane < deg * 8)
                simw[(size_t)lo * NH + lane] = fexp2(wval0 - mm) * ii;
        } else if (deg <= 16) {
            simw[(size_t)lo * NH + lane] = fexp2(wval0 - mm) * ii;          // edges lo..lo+7
            if (lane < (deg - 8) * 8)
                simw[(size_t)(lo + 8) * NH + lane] = fexp2(wval1 - mm) * ii; // edges lo+8..
        } else {
            asm volatile("s_waitcnt vmcnt(0)" ::: "memory");   // drain sim stores
            for (int i = lane; i < deg * 8; i += 64) {
                size_t idx = (size_t)lo * NH + i;          // head = i&7 = lane&7
                float v = simw[idx];
                simw[idx] = fexp2(v - mm) * ii;
            }
        }
    }
}

// ---------------------------------------------------------------- launch
extern "C" void kernel_launch(void* const* d_in, const int* in_sizes, int n_in,
                              void* d_out, int out_size, void* d_ws, size_t ws_size,
                              hipStream_t stream) {
    const float* q    = (const float*)d_in[0];
    const float* k    = (const float*)d_in[1];
    const float* bias = (const float*)d_in[2];
    const float* lnw  = (const float*)d_in[3];
    const float* lnb  = (const float*)d_in[4];
    const float* wq   = (const float*)d_in[5];
    const float* bq   = (const float*)d_in[6];
    const float* wk   = (const float*)d_in[7];
    const float* bk   = (const float*)d_in[8];
    const float* wo   = (const float*)d_in[9];
    const float* bo   = (const float*)d_in[10];
    const int*   src  = (const int*)d_in[11];
    const int*   dst  = (const int*)d_in[12];

    float* out_m = (float*)d_out;                   // [QN][CD] fp32
    float* out_w = out_m + (size_t)QN * CD;         // [NE][NH] fp32 (weights)

    ushort* qn_b = (ushort*)d_ws;                   // [QN][CD]  LN(q) bf16 -> reused as attn_out
    ushort* qp_b = qn_b + (size_t)QN * CD;          // [QN][CD]  qp bf16
    ushort* kp_b = qp_b + (size_t)QN * CD;          // [KVN][CD] kp bf16
    ushort* wb   = kp_b + (size_t)KVN * CD;         // 3 x [256*256] bf16 weights
    int*    rowlo = (int*)(wb + 3 * 65536);         // [QN+1]

    // kb (k converted to bf16) lives in the out_m region: it is consumed by
    // gemm2<0> and out_m is only written by the final gemm2<1>.
    ushort* kb = (ushort*)d_out;                    // [KVN][CD] bf16 (32 MB of 64)

    prep_k<<<dim3(LNB + 192 + RLB + LNB), dim3(256), 0, stream>>>(
        q, k, lnw, lnb, wq, wk, wo, dst, qn_b, kb, wb, rowlo);

    // z=0: qp = LN(q)@wq ; z=1: kp = kb@wk   (both bf16, identical blocks)
    gemm2_k<0, 8><<<dim3(64, 2, 2), dim3(512), 0, stream>>>(
        qn_b, kb, wb, wb + 65536, bq, bk, nullptr, qp_b, kp_b);

    edge_attn_k<<<dim3(QN / 4), dim3(256), 0, stream>>>(
        qp_b, kp_b, bias, src, rowlo, qn_b /*ao*/, out_w);

    // out = attn_out@wo + bo + q
    gemm2_k<1, 4><<<dim3(128, 2, 1), dim3(512), 0, stream>>>(
        qn_b, qn_b, wb + 131072, wb + 131072, bo, bo, q, out_m, out_m);
}

// Round 4
// 185.993 us; speedup vs baseline: 1.1444x; 1.1444x over previous
//
#include <hip/hip_runtime.h>
#include <cmath>

#define QN    65536
#define KVN   65536
#define CD    256
#define NH    8
#define NE    524288
#define SCL   0.0625f      // 1/sqrt(256)
#define LNEPS 1e-5f
#define LOG2E 1.4426950408889634f

typedef __bf16 bf16x8 __attribute__((ext_vector_type(8)));
typedef float  f32x4  __attribute__((ext_vector_type(4)));

__device__ __forceinline__ float b2f(ushort u) {
    return __builtin_bit_cast(float, (unsigned)u << 16);
}
__device__ __forceinline__ ushort f2bf(float f) {
    unsigned u = __builtin_bit_cast(unsigned, f);
    return (ushort)((u + 0x7FFFu + ((u >> 16) & 1u)) >> 16);   // RNE
}

#if __has_builtin(__builtin_amdgcn_exp2f)
__device__ __forceinline__ float fexp2(float x) { return __builtin_amdgcn_exp2f(x); }
#else
__device__ __forceinline__ float fexp2(float x) {
    float r; asm volatile("v_exp_f32 %0, %1" : "=v"(r) : "v"(x)); return r;
}
#endif

#define GLD16(g, l) __builtin_amdgcn_global_load_lds( \
    (const __attribute__((address_space(1))) unsigned int*)(const void*)(g), \
    (__attribute__((address_space(3))) unsigned int*)(void*)(l), 16, 0, 0)

// ---------------------------------------------------------------- fused prep:
// blk [0, LNB):          LN(q) -> bf16 qn           (4 rows/block)
// blk [LNB, LNB+192):    wq|wk|wo fp32 -> bf16      (1024 els/block)
// blk [.., +NE/256):     CSR row_lo fill
// (k->bf16 conversion removed: fused into gemm2's conv path)
#define LNB   (QN / 4)
#define RLB   (NE / 256)
__global__ __launch_bounds__(256) void prep_k(const float* __restrict__ q,
                                              const float* __restrict__ lnw,
                                              const float* __restrict__ lnb,
                                              const float* __restrict__ wq,
                                              const float* __restrict__ wk,
                                              const float* __restrict__ wo,
                                              const int* __restrict__ dst,
                                              ushort* __restrict__ qn,
                                              ushort* __restrict__ wb,
                                              int* __restrict__ row_lo) {
    const int blk = blockIdx.x;
    if (blk < LNB) {
        int row  = (blk << 2) + (threadIdx.x >> 6);
        int lane = threadIdx.x & 63;
        float4 v = *(const float4*)(q + (size_t)row * CD + (lane << 2));
        float s  = v.x + v.y + v.z + v.w;
        float s2 = v.x * v.x + v.y * v.y + v.z * v.z + v.w * v.w;
        #pragma unroll
        for (int m = 1; m < 64; m <<= 1) {
            s  += __shfl_xor(s, m);
            s2 += __shfl_xor(s2, m);
        }
        float mu   = s * (1.0f / CD);
        float rstd = rsqrtf(s2 * (1.0f / CD) - mu * mu + LNEPS);
        float4 w = *(const float4*)(lnw + (lane << 2));
        float4 b = *(const float4*)(lnb + (lane << 2));
        ushort4 o;
        o.x = f2bf((v.x - mu) * rstd * w.x + b.x);
        o.y = f2bf((v.y - mu) * rstd * w.y + b.y);
        o.z = f2bf((v.z - mu) * rstd * w.z + b.z);
        o.w = f2bf((v.w - mu) * rstd * w.w + b.w);
        *(ushort4*)(qn + (size_t)row * CD + (lane << 2)) = o;
    } else if (blk < LNB + 192) {
        int idx4 = ((blk - LNB) * 256 + threadIdx.x) * 4;   // 0 .. 3*65536
        int mat  = idx4 >> 16;
        int off  = idx4 & 65535;
        const float* src = (mat == 0) ? wq : (mat == 1) ? wk : wo;
        float4 v = *(const float4*)(src + off);
        ushort4 o;
        o.x = f2bf(v.x); o.y = f2bf(v.y); o.z = f2bf(v.z); o.w = f2bf(v.w);
        *(ushort4*)(wb + idx4) = o;
    } else {
        int e = (blk - LNB - 192) * 256 + threadIdx.x;
        int d     = dst[e];
        int dprev = (e == 0) ? -1 : dst[e - 1];
        for (int qq = dprev + 1; qq <= d; ++qq) row_lo[qq] = e;
        if (e == NE - 1)
            for (int qq = d + 1; qq <= QN; ++qq) row_lo[qq] = NE;
    }
}

// ---------------------------------------------------------------- persistent bf16 GEMM
// One block per CU (LDS 128 KB), 512 threads = 8 waves (2m x 4n), tile 128x128.
// B panel (256x128-col slice of the weight matrix, 64 KB) loaded into LDS ONCE.
// A streamed through an 8-slot LDS ring (8 KB/slot); ONE barrier per K-step.
// z==0 path: A bf16 via global_load_lds, stage-ahead-6, counted vmcnt (proven R2).
// z==1 path (conv): A fp32, register-staged 2-KSTEPs-ahead: loads for slot KT+6
//   issue at KSTEP KT, convert+ds_write at KSTEP KT+2 (slot KT+4 naming).
//   Reg-dependency waits are compiler-inserted; LDS visibility via the
//   lgkmcnt(0)+barrier chain (4 barriers between write and first read).
// Swapped MFMA operands (mfma(bg, af)) -> 4 consecutive C-cols per lane ->
// vectorized epilogue stores keep post-epilogue waits counted.
// EPI 0: bf16 out (E=8).  EPI 1: f32 out + resid (E=16).
template<int EPI, int NT>
__global__ __launch_bounds__(512) void gemm2_k(const ushort* __restrict__ A0,
                                               const float* __restrict__ Afp,
                                               const ushort* __restrict__ B0,
                                               const ushort* __restrict__ B1,
                                               const float* __restrict__ bias0,
                                               const float* __restrict__ bias1,
                                               const float* __restrict__ resid,
                                               void* __restrict__ C0,
                                               void* __restrict__ C1) {
    const bool conv = (blockIdx.z != 0);
    const ushort* Ap   = A0;
    const ushort* B    = conv ? B1 : B0;
    const float*  bias = conv ? bias1 : bias0;
    void*         Cout = conv ? C1 : C0;

    __shared__ __align__(16) ushort Bs[8][4096];   // 64 KB: full B panel, 8 k-slices
    __shared__ __align__(16) ushort As[8][4096];   // 64 KB: A ring, 8 slots

    const int t    = threadIdx.x;
    const int lane = t & 63;
    const int wid  = t >> 6;             // 0..7
    const int wm   = wid & 1;            // 2 wave-rows
    const int wn   = wid >> 1;           // 4 wave-cols
    const size_t bn  = (size_t)blockIdx.y * 128;
    size_t bm = (size_t)blockIdx.x * (NT * 128);

    const int sr = t >> 2;               // 0..127 staging row
    const int sc = (t & 3) * 8;          // staging col (8 els)

    constexpr int E = (EPI == 0) ? 8 : 16;   // epilogue vmem instrs

    f32x4 acc[4][2] = {};
    f32x4 biasv[2];
    #pragma unroll
    for (int ni = 0; ni < 2; ++ni)
        biasv[ni] = *(const f32x4*)(bias + bn + wn * 32 + ni * 16 + ((lane >> 4) << 2));

    float4 pa0, pa1, pb0, pb1;           // conv-path 2-ahead reg pipeline (even/odd KT)

    // ---- prologue
    #pragma unroll
    for (int s = 0; s < 8; ++s)
        GLD16(B + (bn + sr) * CD + (s << 5) + sc, &Bs[s][wid << 9]);
    if (conv) {
        // slots 0..3: load fp32, convert, ds_write
        float4 c0[4], c1[4];
        #pragma unroll
        for (int s = 0; s < 4; ++s) {
            const float* ga = Afp + (bm + sr) * CD + (s << 5) + sc;
            c0[s] = *(const float4*)ga;
            c1[s] = *(const float4*)(ga + 4);
        }
        #pragma unroll
        for (int s = 0; s < 4; ++s) {
            union { ushort u[8]; uint4 v; } pk;
            pk.u[0] = f2bf(c0[s].x); pk.u[1] = f2bf(c0[s].y); pk.u[2] = f2bf(c0[s].z); pk.u[3] = f2bf(c0[s].w);
            pk.u[4] = f2bf(c1[s].x); pk.u[5] = f2bf(c1[s].y); pk.u[6] = f2bf(c1[s].z); pk.u[7] = f2bf(c1[s].w);
            *(uint4*)&As[s][t * 8] = pk.v;
        }
        { const float* ga = Afp + (bm + sr) * CD + (4 << 5) + sc; pa0 = *(const float4*)ga; pa1 = *(const float4*)(ga + 4); }
        { const float* ga = Afp + (bm + sr) * CD + (5 << 5) + sc; pb0 = *(const float4*)ga; pb1 = *(const float4*)(ga + 4); }
    } else {
        #pragma unroll
        for (int s = 0; s < 6; ++s)
            GLD16(Ap + (bm + sr) * CD + (s << 5) + sc, &As[s][wid << 9]);
    }
    asm volatile("" : "+v"(biasv[0]), "+v"(biasv[1]));   // materialize bias now

    // KSTEP(KT, VM, LG, CG, FIRSTK):
    //  conv: [CG] convert regs(slot KT+4) -> LDS; [LG] load regs(slot KT+6);
    //        barrier with lgkmcnt(0) only (vmcnt(0) if FIRSTK, to drain B panel).
    //  z0:   [LG] GLD16 slot KT+6; barrier with counted vmcnt(VM)+lgkmcnt(0).
    //  then: 6 ds_read_b128 + 8 MFMA on slot KT.
#define KSTEP(KT, VM, LG, CG, FIRSTK)                                                 \
  {                                                                                   \
    if (conv) {                                                                       \
      if (CG) {                                                                       \
        union { ushort u[8]; uint4 v; } pk_;                                          \
        if ((KT) & 1) {                                                               \
          pk_.u[0] = f2bf(pb0.x); pk_.u[1] = f2bf(pb0.y); pk_.u[2] = f2bf(pb0.z); pk_.u[3] = f2bf(pb0.w); \
          pk_.u[4] = f2bf(pb1.x); pk_.u[5] = f2bf(pb1.y); pk_.u[6] = f2bf(pb1.z); pk_.u[7] = f2bf(pb1.w); \
        } else {                                                                      \
          pk_.u[0] = f2bf(pa0.x); pk_.u[1] = f2bf(pa0.y); pk_.u[2] = f2bf(pa0.z); pk_.u[3] = f2bf(pa0.w); \
          pk_.u[4] = f2bf(pa1.x); pk_.u[5] = f2bf(pa1.y); pk_.u[6] = f2bf(pa1.z); pk_.u[7] = f2bf(pa1.w); \
        }                                                                             \
        *(uint4*)&As[((KT) + 4) & 7][t * 8] = pk_.v;                                  \
      }                                                                               \
      if (LG) {                                                                       \
        const float* ga_ = Afp + (bm + (((KT) >= 2) ? 128 : 0) + sr) * CD             \
                           + ((((KT) + 6) & 7) << 5) + sc;                            \
        if ((KT) & 1) { pb0 = *(const float4*)ga_; pb1 = *(const float4*)(ga_ + 4); } \
        else          { pa0 = *(const float4*)ga_; pa1 = *(const float4*)(ga_ + 4); } \
      }                                                                               \
      if (FIRSTK) asm volatile("s_waitcnt vmcnt(0) lgkmcnt(0)\n\ts_barrier" ::: "memory"); \
      else        asm volatile("s_waitcnt lgkmcnt(0)\n\ts_barrier" ::: "memory");     \
    } else {                                                                          \
      if (LG) {                                                                       \
        const ushort* ga_ = Ap + (bm + (((KT) >= 2) ? 128 : 0) + sr) * CD             \
                            + ((((KT) + 6) & 7) << 5) + sc;                           \
        GLD16(ga_, &As[((KT) + 6) & 7][wid << 9]);                                    \
      }                                                                               \
      asm volatile("s_waitcnt vmcnt(%0) lgkmcnt(0)\n\ts_barrier" :: "i"(VM) : "memory"); \
    }                                                                                 \
    {                                                                                 \
      const int kq_ = (lane >> 4) << 3;                                               \
      bf16x8 af_[4], bg_[2];                                                          \
      _Pragma("unroll")                                                               \
      for (int mi = 0; mi < 4; ++mi)                                                  \
        af_[mi] = *(const bf16x8*)&As[(KT) & 7][((wm * 64 + mi * 16 + (lane & 15)) << 5) + kq_]; \
      _Pragma("unroll")                                                               \
      for (int ni = 0; ni < 2; ++ni)                                                  \
        bg_[ni] = *(const bf16x8*)&Bs[(KT)][((wn * 32 + ni * 16 + (lane & 15)) << 5) + kq_];     \
      _Pragma("unroll")                                                               \
      for (int mi = 0; mi < 4; ++mi)                                                  \
        _Pragma("unroll")                                                             \
        for (int ni = 0; ni < 2; ++ni)                                                \
          acc[mi][ni] = __builtin_amdgcn_mfma_f32_16x16x32_bf16(bg_[ni], af_[mi], acc[mi][ni], 0, 0, 0); \
    }                                                                                 \
  }

#define EPILOG()                                                                      \
  {                                                                                   \
    _Pragma("unroll")                                                                 \
    for (int mi = 0; mi < 4; ++mi) {                                                  \
      const size_t row_ = bm + wm * 64 + mi * 16 + (lane & 15);                       \
      _Pragma("unroll")                                                               \
      for (int ni = 0; ni < 2; ++ni) {                                                \
        const size_t col_ = bn + wn * 32 + ni * 16 + ((lane >> 4) << 2);              \
        if (EPI == 0) {                                                               \
          ushort4 o_;                                                                 \
          o_.x = f2bf(acc[mi][ni][0] + biasv[ni][0]);                                 \
          o_.y = f2bf(acc[mi][ni][1] + biasv[ni][1]);                                 \
          o_.z = f2bf(acc[mi][ni][2] + biasv[ni][2]);                                 \
          o_.w = f2bf(acc[mi][ni][3] + biasv[ni][3]);                                 \
          *(ushort4*)((ushort*)Cout + row_ * CD + col_) = o_;                         \
        } else {                                                                      \
          f32x4 rs_ = *(const f32x4*)(resid + row_ * CD + col_);                      \
          f32x4 o_;                                                                   \
          o_[0] = acc[mi][ni][0] + biasv[ni][0] + rs_[0];                             \
          o_[1] = acc[mi][ni][1] + biasv[ni][1] + rs_[1];                             \
          o_[2] = acc[mi][ni][2] + biasv[ni][2] + rs_[2];                             \
          o_[3] = acc[mi][ni][3] + biasv[ni][3] + rs_[3];                             \
          *(f32x4*)((float*)Cout + row_ * CD + col_) = o_;                            \
        }                                                                             \
        acc[mi][ni] = (f32x4){0.f, 0.f, 0.f, 0.f};                                    \
      }                                                                               \
    }                                                                                 \
    asm volatile("" ::: "memory");                                                    \
  }

    // ---- tile 0
    KSTEP(0, 6, 1, 1, 1) KSTEP(1, 6, 1, 1, 0) KSTEP(2, 6, 1, 1, 0) KSTEP(3, 6, 1, 1, 0)
    KSTEP(4, 6, 1, 1, 0) KSTEP(5, 6, 1, 1, 0) KSTEP(6, 6, 1, 1, 0) KSTEP(7, 6, 1, 1, 0)
    EPILOG();
    bm += 128;

    // ---- middle tiles
    for (int tt = 1; tt < NT - 1; ++tt) {
        KSTEP(0, 6 + E, 1, 1, 0) KSTEP(1, 6 + E, 1, 1, 0) KSTEP(2, 6 + E, 1, 1, 0) KSTEP(3, 6 + E, 1, 1, 0)
        KSTEP(4, 6 + E, 1, 1, 0) KSTEP(5, 6 + E, 1, 1, 0) KSTEP(6, 6, 1, 1, 0)     KSTEP(7, 6, 1, 1, 0)
        EPILOG();
        bm += 128;
    }

    // ---- last tile: loads stop after kt1; converts stop after kt3
    KSTEP(0, 6 + E, 1, 1, 0) KSTEP(1, 6 + E, 1, 1, 0) KSTEP(2, 5 + E, 0, 1, 0) KSTEP(3, 4 + E, 0, 1, 0)
    KSTEP(4, 3 + E, 0, 0, 0) KSTEP(5, 2 + E, 0, 0, 0) KSTEP(6, 1, 0, 0, 0)     KSTEP(7, 0, 0, 0, 0)
    EPILOG();

#undef KSTEP
#undef EPILOG
}

// ---------------------------------------------------------------- edge attention
// Proven R2 kernel, byte-identical (1-wave blocks retire independently; the
// compiler software-pipelines the chunk loop; deg<=16 weights in-register).
// R3's 4-query/256-thread + chunk-deferred variant REGRESSED (70->112us:
// block-granular retirement + VGPR 36->48 dropped occupancy 63->42%).
__global__ __launch_bounds__(64) void edge_attn_k(const ushort* __restrict__ qp,
                                                  const ushort* __restrict__ kp,
                                                  const float* __restrict__ bias,
                                                  const int* __restrict__ src,
                                                  const int* __restrict__ row_lo,
                                                  ushort* __restrict__ ao,
                                                  float* __restrict__ simw) {
    const int q    = blockIdx.x;
    const int lane = threadIdx.x;
    const int lo = row_lo[q];
    const int hi = row_lo[q + 1];
    const int deg = hi - lo;
    const float SC2 = SCL * LOG2E;

    ushort4 qu = *(const ushort4*)(qp + (size_t)q * CD + (lane << 2));
    float4 qv = {b2f(qu.x) * SC2, b2f(qu.y) * SC2, b2f(qu.z) * SC2, b2f(qu.w) * SC2};
    float4 acc = {0.f, 0.f, 0.f, 0.f};
    float m = -INFINITY, s = 0.f;
    float wval0 = 0.f, wval1 = 0.f;      // chunk-0 / chunk-1 transposed sims

    for (int base = lo; base < hi; base += 8) {
        const int cnum = (base - lo) >> 3;
        // ---- load phase: 1 src chunk + 1 bias chunk + up to 8 kp rows
        int sv = 0;
        if (lane < 8 && base + lane < hi) sv = src[base + lane];
        float bch = 0.f;
        if (lane < (hi - base) * 8) bch = bias[(size_t)base * NH + lane] * SC2;
        ushort4 ku[8];
        #pragma unroll
        for (int i = 0; i < 8; ++i) {
            if (base + i < hi) {
                int sidx = __shfl(sv, i);
                ku[i] = *(const ushort4*)(kp + (size_t)sidx * CD + (lane << 2));
            }
        }
        // ---- per-edge compute (online softmax, log2 domain)
        #pragma unroll
        for (int i = 0; i < 8; ++i) {
            if (base + i < hi) {
                float4 kv = {b2f(ku[i].x), b2f(ku[i].y), b2f(ku[i].z), b2f(ku[i].w)};
                float d = qv.x * kv.x + qv.y * kv.y + qv.z * kv.z + qv.w * kv.w;
                d += __shfl_xor(d, 1);
                d += __shfl_xor(d, 2);
                d += __shfl_xor(d, 4);
                float bvi = __shfl(bch, (i << 3) + (lane >> 3));
                float sim = d + bvi;                       // log2 domain
                float tw = __shfl(sim, (lane & 7) << 3);   // capture for weights output
                bool mine = ((lane >> 3) == i);
                if (deg <= 16) {
                    if (cnum == 0) wval0 = mine ? tw : wval0;
                    else           wval1 = mine ? tw : wval1;
                } else {
                    wval0 = mine ? tw : wval0;             // rolling (staged per chunk)
                }
                float mnew  = fmaxf(m, sim);
                float scale = fexp2(m - mnew);             // first edge: exp2(-inf)=0
                float ex    = fexp2(sim - mnew);
                s = s * scale + ex;
                acc.x = acc.x * scale + ex * kv.x;
                acc.y = acc.y * scale + ex * kv.y;
                acc.z = acc.z * scale + ex * kv.z;
                acc.w = acc.w * scale + ex * kv.w;
                m = mnew;
            }
        }
        // ---- stage raw (log2) sims only for deg>16 queries (rare)
        if (deg > 16) {
            int lim = hi - base; if (lim > 8) lim = 8;
            if (lane < lim * 8) simw[(size_t)base * NH + lane] = wval0;
        }
    }

    float ws  = s + 1e-8f;
    float inv = 1.0f / ws;
    ushort4 o;
    o.x = f2bf(acc.x * inv);
    o.y = f2bf(acc.y * inv);
    o.z = f2bf(acc.z * inv);
    o.w = f2bf(acc.w * inv);
    *(ushort4*)(ao + (size_t)q * CD + (lane << 2)) = o;

    if (deg > 0) {
        const float mm = __shfl(m,   (lane & 7) << 3);     // state of head lane&7
        const float ii = __shfl(inv, (lane & 7) << 3);
        if (deg <= 8) {
            if (lane < deg * 8)
                simw[(size_t)lo * NH + lane] = fexp2(wval0 - mm) * ii;
        } else if (deg <= 16) {
            simw[(size_t)lo * NH + lane] = fexp2(wval0 - mm) * ii;          // edges lo..lo+7
            if (lane < (deg - 8) * 8)
                simw[(size_t)(lo + 8) * NH + lane] = fexp2(wval1 - mm) * ii; // edges lo+8..
        } else {
            asm volatile("s_waitcnt vmcnt(0)" ::: "memory");   // drain sim stores
            for (int i = lane; i < deg * 8; i += 64) {
                size_t idx = (size_t)lo * NH + i;          // head = i&7 = lane&7
                float v = simw[idx];
                simw[idx] = fexp2(v - mm) * ii;
            }
        }
    }
}

// ---------------------------------------------------------------- launch
extern "C" void kernel_launch(void* const* d_in, const int* in_sizes, int n_in,
                              void* d_out, int out_size, void* d_ws, size_t ws_size,
                              hipStream_t stream) {
    const float* q    = (const float*)d_in[0];
    const float* k    = (const float*)d_in[1];
    const float* bias = (const float*)d_in[2];
    const float* lnw  = (const float*)d_in[3];
    const float* lnb  = (const float*)d_in[4];
    const float* wq   = (const float*)d_in[5];
    const float* bq   = (const float*)d_in[6];
    const float* wk   = (const float*)d_in[7];
    const float* bk   = (const float*)d_in[8];
    const float* wo   = (const float*)d_in[9];
    const float* bo   = (const float*)d_in[10];
    const int*   src  = (const int*)d_in[11];
    const int*   dst  = (const int*)d_in[12];

    float* out_m = (float*)d_out;                   // [QN][CD] fp32
    float* out_w = out_m + (size_t)QN * CD;         // [NE][NH] fp32 (weights)

    ushort* qn_b = (ushort*)d_ws;                   // [QN][CD]  LN(q) bf16 -> reused as attn_out
    ushort* qp_b = qn_b + (size_t)QN * CD;          // [QN][CD]  qp bf16
    ushort* kp_b = qp_b + (size_t)QN * CD;          // [KVN][CD] kp bf16
    ushort* wb   = kp_b + (size_t)KVN * CD;         // 3 x [256*256] bf16 weights
    int*    rowlo = (int*)(wb + 3 * 65536);         // [QN+1]

    prep_k<<<dim3(LNB + 192 + RLB), dim3(256), 0, stream>>>(
        q, lnw, lnb, wq, wk, wo, dst, qn_b, wb, rowlo);

    // z=0: qp = LN(q)@wq (bf16 A via GLD16 ring); z=1: kp = k@wk (fp32 A,
    // conversion fused into the register staging -> no kb round-trip)
    gemm2_k<0, 8><<<dim3(64, 2, 2), dim3(512), 0, stream>>>(
        qn_b, k, wb, wb + 65536, bq, bk, nullptr, qp_b, kp_b);

    edge_attn_k<<<dim3(QN), dim3(64), 0, stream>>>(
        qp_b, kp_b, bias, src, rowlo, qn_b /*ao*/, out_w);

    // out = attn_out@wo + bo + q
    gemm2_k<1, 4><<<dim3(128, 2, 1), dim3(512), 0, stream>>>(
        qn_b, nullptr, wb + 131072, wb + 131072, bo, bo, q, out_m, out_m);
}

// Round 5
// 175.861 us; speedup vs baseline: 1.2104x; 1.0576x over previous
//
#include <hip/hip_runtime.h>
#include <cmath>

#define QN    65536
#define KVN   65536
#define CD    256
#define NH    8
#define NE    524288
#define SCL   0.0625f      // 1/sqrt(256)
#define LNEPS 1e-5f
#define LOG2E 1.4426950408889634f

typedef __bf16 bf16x8 __attribute__((ext_vector_type(8)));
typedef float  f32x4  __attribute__((ext_vector_type(4)));

__device__ __forceinline__ float b2f(ushort u) {
    return __builtin_bit_cast(float, (unsigned)u << 16);
}
__device__ __forceinline__ float blo(unsigned u) {
    return __builtin_bit_cast(float, u << 16);
}
__device__ __forceinline__ float bhi(unsigned u) {
    return __builtin_bit_cast(float, u & 0xFFFF0000u);
}
__device__ __forceinline__ ushort f2bf(float f) {
    unsigned u = __builtin_bit_cast(unsigned, f);
    return (ushort)((u + 0x7FFFu + ((u >> 16) & 1u)) >> 16);   // RNE
}

#if __has_builtin(__builtin_amdgcn_exp2f)
__device__ __forceinline__ float fexp2(float x) { return __builtin_amdgcn_exp2f(x); }
#else
__device__ __forceinline__ float fexp2(float x) {
    float r; asm volatile("v_exp_f32 %0, %1" : "=v"(r) : "v"(x)); return r;
}
#endif

#define GLD16(g, l) __builtin_amdgcn_global_load_lds( \
    (const __attribute__((address_space(1))) unsigned int*)(const void*)(g), \
    (__attribute__((address_space(3))) unsigned int*)(void*)(l), 16, 0, 0)

// ---------------------------------------------------------------- fused prep:
// blk [0, LNB):          LN(q) -> bf16 qn           (4 rows/block)
// blk [LNB, LNB+192):    wq|wk|wo fp32 -> bf16      (1024 els/block)
// blk [.., +NE/256):     CSR row_lo fill
// blk [.., +LNB):        k fp32 -> bf16 kb          (4 rows/block)
#define LNB   (QN / 4)
#define RLB   (NE / 256)
__global__ __launch_bounds__(256) void prep_k(const float* __restrict__ q,
                                              const float* __restrict__ k,
                                              const float* __restrict__ lnw,
                                              const float* __restrict__ lnb,
                                              const float* __restrict__ wq,
                                              const float* __restrict__ wk,
                                              const float* __restrict__ wo,
                                              const int* __restrict__ dst,
                                              ushort* __restrict__ qn,
                                              ushort* __restrict__ kb,
                                              ushort* __restrict__ wb,
                                              int* __restrict__ row_lo) {
    const int blk = blockIdx.x;
    if (blk < LNB) {
        int row  = (blk << 2) + (threadIdx.x >> 6);
        int lane = threadIdx.x & 63;
        float4 v = *(const float4*)(q + (size_t)row * CD + (lane << 2));
        float s  = v.x + v.y + v.z + v.w;
        float s2 = v.x * v.x + v.y * v.y + v.z * v.z + v.w * v.w;
        #pragma unroll
        for (int m = 1; m < 64; m <<= 1) {
            s  += __shfl_xor(s, m);
            s2 += __shfl_xor(s2, m);
        }
        float mu   = s * (1.0f / CD);
        float rstd = rsqrtf(s2 * (1.0f / CD) - mu * mu + LNEPS);
        float4 w = *(const float4*)(lnw + (lane << 2));
        float4 b = *(const float4*)(lnb + (lane << 2));
        ushort4 o;
        o.x = f2bf((v.x - mu) * rstd * w.x + b.x);
        o.y = f2bf((v.y - mu) * rstd * w.y + b.y);
        o.z = f2bf((v.z - mu) * rstd * w.z + b.z);
        o.w = f2bf((v.w - mu) * rstd * w.w + b.w);
        *(ushort4*)(qn + (size_t)row * CD + (lane << 2)) = o;
    } else if (blk < LNB + 192) {
        int idx4 = ((blk - LNB) * 256 + threadIdx.x) * 4;   // 0 .. 3*65536
        int mat  = idx4 >> 16;
        int off  = idx4 & 65535;
        const float* src = (mat == 0) ? wq : (mat == 1) ? wk : wo;
        float4 v = *(const float4*)(src + off);
        ushort4 o;
        o.x = f2bf(v.x); o.y = f2bf(v.y); o.z = f2bf(v.z); o.w = f2bf(v.w);
        *(ushort4*)(wb + idx4) = o;
    } else if (blk < LNB + 192 + RLB) {
        int e = (blk - LNB - 192) * 256 + threadIdx.x;
        int d     = dst[e];
        int dprev = (e == 0) ? -1 : dst[e - 1];
        for (int qq = dprev + 1; qq <= d; ++qq) row_lo[qq] = e;
        if (e == NE - 1)
            for (int qq = d + 1; qq <= QN; ++qq) row_lo[qq] = NE;
    } else {
        int row  = ((blk - LNB - 192 - RLB) << 2) + (threadIdx.x >> 6);
        int lane = threadIdx.x & 63;
        float4 v = *(const float4*)(k + (size_t)row * CD + (lane << 2));
        ushort4 o;
        o.x = f2bf(v.x); o.y = f2bf(v.y); o.z = f2bf(v.z); o.w = f2bf(v.w);
        *(ushort4*)(kb + (size_t)row * CD + (lane << 2)) = o;
    }
}

// ---------------------------------------------------------------- persistent bf16 GEMM
// Proven R2 kernel, byte-identical. One block per CU (LDS 128 KB), 512 threads
// = 8 waves (2m x 4n), tile 128x128. B panel in LDS once; A via 8-slot GLD16
// ring, stage-ahead-6, counted vmcnt; one barrier per K-step; swapped-operand
// MFMA -> vectorized epilogue. EPI 0: bf16 out (E=8). EPI 1: f32 + resid (E=16).
template<int EPI, int NT>
__global__ __launch_bounds__(512) void gemm2_k(const ushort* __restrict__ A0,
                                               const ushort* __restrict__ A1,
                                               const ushort* __restrict__ B0,
                                               const ushort* __restrict__ B1,
                                               const float* __restrict__ bias0,
                                               const float* __restrict__ bias1,
                                               const float* __restrict__ resid,
                                               void* __restrict__ C0,
                                               void* __restrict__ C1) {
    const bool second = (blockIdx.z != 0);
    const ushort* Ap   = second ? A1 : A0;
    const ushort* B    = second ? B1 : B0;
    const float*  bias = second ? bias1 : bias0;
    void*         Cout = second ? C1 : C0;

    __shared__ __align__(16) ushort Bs[8][4096];   // 64 KB: full B panel, 8 k-slices
    __shared__ __align__(16) ushort As[8][4096];   // 64 KB: A ring, 8 slots

    const int t    = threadIdx.x;
    const int lane = t & 63;
    const int wid  = t >> 6;             // 0..7
    const int wm   = wid & 1;            // 2 wave-rows
    const int wn   = wid >> 1;           // 4 wave-cols
    const size_t bn  = (size_t)blockIdx.y * 128;
    size_t bm = (size_t)blockIdx.x * (NT * 128);

    const int sr = t >> 2;               // 0..127 staging row
    const int sc = (t & 3) * 8;          // staging col (8 elems = 16B)

    constexpr int E = (EPI == 0) ? 8 : 16;   // epilogue vmem instrs

    f32x4 acc[4][2] = {};
    f32x4 biasv[2];
    #pragma unroll
    for (int ni = 0; ni < 2; ++ni)
        biasv[ni] = *(const f32x4*)(bias + bn + wn * 32 + ni * 16 + ((lane >> 4) << 2));

    // ---- prologue: whole B panel + A slots 0..5
    #pragma unroll
    for (int s = 0; s < 8; ++s)
        GLD16(B + (bn + sr) * CD + (s << 5) + sc, &Bs[s][wid << 9]);
    #pragma unroll
    for (int s = 0; s < 6; ++s)
        GLD16(Ap + (bm + sr) * CD + (s << 5) + sc, &As[s][wid << 9]);
    asm volatile("" : "+v"(biasv[0]), "+v"(biasv[1]));

#define KSTEP(KT, VM, GUARD)                                                          \
  {                                                                                   \
    if (GUARD) {                                                                      \
      const ushort* ga_ = Ap + (bm + (((KT) >= 2) ? 128 : 0) + sr) * CD               \
                          + ((((KT) + 6) & 7) << 5) + sc;                             \
      GLD16(ga_, &As[((KT) + 6) & 7][wid << 9]);                                      \
    }                                                                                 \
    asm volatile("s_waitcnt vmcnt(%0) lgkmcnt(0)\n\ts_barrier" :: "i"(VM) : "memory");\
    {                                                                                 \
      const int kq_ = (lane >> 4) << 3;                                               \
      bf16x8 af_[4], bg_[2];                                                          \
      _Pragma("unroll")                                                               \
      for (int mi = 0; mi < 4; ++mi)                                                  \
        af_[mi] = *(const bf16x8*)&As[(KT) & 7][((wm * 64 + mi * 16 + (lane & 15)) << 5) + kq_]; \
      _Pragma("unroll")                                                               \
      for (int ni = 0; ni < 2; ++ni)                                                  \
        bg_[ni] = *(const bf16x8*)&Bs[(KT)][((wn * 32 + ni * 16 + (lane & 15)) << 5) + kq_];     \
      _Pragma("unroll")                                                               \
      for (int mi = 0; mi < 4; ++mi)                                                  \
        _Pragma("unroll")                                                             \
        for (int ni = 0; ni < 2; ++ni)                                                \
          acc[mi][ni] = __builtin_amdgcn_mfma_f32_16x16x32_bf16(bg_[ni], af_[mi], acc[mi][ni], 0, 0, 0); \
    }                                                                                 \
  }

#define EPILOG()                                                                      \
  {                                                                                   \
    _Pragma("unroll")                                                                 \
    for (int mi = 0; mi < 4; ++mi) {                                                  \
      const size_t row_ = bm + wm * 64 + mi * 16 + (lane & 15);                       \
      _Pragma("unroll")                                                               \
      for (int ni = 0; ni < 2; ++ni) {                                                \
        const size_t col_ = bn + wn * 32 + ni * 16 + ((lane >> 4) << 2);              \
        if (EPI == 0) {                                                               \
          ushort4 o_;                                                                 \
          o_.x = f2bf(acc[mi][ni][0] + biasv[ni][0]);                                 \
          o_.y = f2bf(acc[mi][ni][1] + biasv[ni][1]);                                 \
          o_.z = f2bf(acc[mi][ni][2] + biasv[ni][2]);                                 \
          o_.w = f2bf(acc[mi][ni][3] + biasv[ni][3]);                                 \
          *(ushort4*)((ushort*)Cout + row_ * CD + col_) = o_;                         \
        } else {                                                                      \
          f32x4 rs_ = *(const f32x4*)(resid + row_ * CD + col_);                      \
          f32x4 o_;                                                                   \
          o_[0] = acc[mi][ni][0] + biasv[ni][0] + rs_[0];                             \
          o_[1] = acc[mi][ni][1] + biasv[ni][1] + rs_[1];                             \
          o_[2] = acc[mi][ni][2] + biasv[ni][2] + rs_[2];                             \
          o_[3] = acc[mi][ni][3] + biasv[ni][3] + rs_[3];                             \
          *(f32x4*)((float*)Cout + row_ * CD + col_) = o_;                            \
        }                                                                             \
        acc[mi][ni] = (f32x4){0.f, 0.f, 0.f, 0.f};                                    \
      }                                                                               \
    }                                                                                 \
    asm volatile("" ::: "memory");                                                    \
  }

    // ---- tile 0
    KSTEP(0, 6, 1) KSTEP(1, 6, 1) KSTEP(2, 6, 1) KSTEP(3, 6, 1)
    KSTEP(4, 6, 1) KSTEP(5, 6, 1) KSTEP(6, 6, 1) KSTEP(7, 6, 1)
    EPILOG();
    bm += 128;

    // ---- middle tiles
    for (int tt = 1; tt < NT - 1; ++tt) {
        KSTEP(0, 6 + E, 1) KSTEP(1, 6 + E, 1) KSTEP(2, 6 + E, 1) KSTEP(3, 6 + E, 1)
        KSTEP(4, 6 + E, 1) KSTEP(5, 6 + E, 1) KSTEP(6, 6, 1)     KSTEP(7, 6, 1)
        EPILOG();
        bm += 128;
    }

    // ---- last tile
    KSTEP(0, 6 + E, 1) KSTEP(1, 6 + E, 1) KSTEP(2, 5 + E, 0) KSTEP(3, 4 + E, 0)
    KSTEP(4, 3 + E, 0) KSTEP(5, 2 + E, 0) KSTEP(6, 1, 0)     KSTEP(7, 0, 0)
    EPILOG();

#undef KSTEP
#undef EPILOG
}

// ---------------------------------------------------------------- edge attention
// v4: lane = (edge-slot e, head h) = e*8+h.  Each lane owns one (edge,head):
// loads 64 B of the kp row (8 lanes jointly cover the full 512-B row), computes
// its 32-ch dot with ZERO shuffles, reads bias[base*8+lane] directly, and the
// per-head online softmax costs 3 shfl_xor per CHUNK (not per edge).  simw is
// directly lane-mapped.  Per-chunk wave-instrs ~800 -> ~260.  Value partials
// accumulate per-lane (32 f32); one LDS transpose-reduce per query at the end.
// 1 wave/block kept (R3 lesson: block-granular retirement kills it).
__global__ __launch_bounds__(64) void edge_attn_k(const ushort* __restrict__ qp,
                                                  const ushort* __restrict__ kp,
                                                  const float* __restrict__ bias,
                                                  const int* __restrict__ src,
                                                  const int* __restrict__ row_lo,
                                                  ushort* __restrict__ ao,
                                                  float* __restrict__ simw) {
    const int q    = blockIdx.x;
    const int lane = threadIdx.x;
    const int e    = lane >> 3;          // edge slot 0..7
    const int h    = lane & 7;           // head
    const int lo = row_lo[q];
    const int hi = row_lo[q + 1];
    const int deg = hi - lo;
    const float SC2 = SCL * LOG2E;

    __shared__ __align__(16) float red[64 * 36];   // stride 36 f32: 16B-aligned rows

    // raw q channels h*32 .. h*32+31 (16 bf16-pairs)
    uint4 qr[4];
    {
        const uint4* qrp = (const uint4*)(qp + (size_t)q * CD + (h << 5));
        qr[0] = qrp[0]; qr[1] = qrp[1]; qr[2] = qrp[2]; qr[3] = qrp[3];
    }

    f32x4 acc4[8] = {};                  // 32 channels, per-lane partial
    float m = -INFINITY, s = 0.f;
    float wval0 = -INFINITY, wval1 = -INFINITY;

    for (int base = lo; base < hi; base += 8) {
        const bool act = (base + e) < hi;
        int   sv = 0;
        float bv = 0.f;
        if (act) {
            sv = src[base + e];                                  // 8-lane broadcast
            bv = bias[(size_t)base * NH + lane] * SC2;           // = bias[base+e][h]
        }
        uint4 ku[4] = {};    // zeros: inactive lanes contribute 0 (no NaN)
        if (act) {
            const uint4* kr = (const uint4*)(kp + (size_t)sv * CD + (h << 5));
            ku[0] = kr[0]; ku[1] = kr[1]; ku[2] = kr[2]; ku[3] = kr[3];
        }
        // 32-channel dot, no shuffles
        float d = 0.f;
        #pragma unroll
        for (int j = 0; j < 4; ++j) {
            const unsigned qu[4] = {qr[j].x, qr[j].y, qr[j].z, qr[j].w};
            const unsigned kw[4] = {ku[j].x, ku[j].y, ku[j].z, ku[j].w};
            #pragma unroll
            for (int w = 0; w < 4; ++w) {
                d = fmaf(blo(qu[w]), blo(kw[w]), d);
                d = fmaf(bhi(qu[w]), bhi(kw[w]), d);
            }
        }
        float sim = act ? fmaf(d, SC2, bv) : -INFINITY;          // log2 domain

        // per-head chunk max across edge-slot lanes (xor 8/16/32 keeps h fixed)
        float cmax = sim;
        cmax = fmaxf(cmax, __shfl_xor(cmax, 8));
        cmax = fmaxf(cmax, __shfl_xor(cmax, 16));
        cmax = fmaxf(cmax, __shfl_xor(cmax, 32));
        const float mnew  = fmaxf(m, cmax);
        const float scale = fexp2(m - mnew);     // first chunk: exp2(-inf)=0
        const float ex    = fexp2(sim - mnew);   // inactive: exp2(-inf)=0
        s = s * scale + ex;
        #pragma unroll
        for (int jj = 0; jj < 8; ++jj) {
            acc4[jj][0] *= scale; acc4[jj][1] *= scale;
            acc4[jj][2] *= scale; acc4[jj][3] *= scale;
        }
        #pragma unroll
        for (int j = 0; j < 4; ++j) {
            const unsigned kw[4] = {ku[j].x, ku[j].y, ku[j].z, ku[j].w};
            #pragma unroll
            for (int w = 0; w < 4; ++w) {
                const int qd = j * 2 + (w >> 1);
                const int el = (w & 1) * 2;
                acc4[qd][el]     = fmaf(ex, blo(kw[w]), acc4[qd][el]);
                acc4[qd][el + 1] = fmaf(ex, bhi(kw[w]), acc4[qd][el + 1]);
            }
        }
        m = mnew;

        // weights capture: sim IS simw[base*8+lane]
        if (deg <= 16) {
            if (base == lo) wval0 = sim; else wval1 = sim;
        } else if (act) {
            simw[(size_t)base * NH + lane] = sim;   // raw log2 sims staged
        }
    }

    // per-head denominator across edge-slot lanes
    s += __shfl_xor(s, 8);
    s += __shfl_xor(s, 16);
    s += __shfl_xor(s, 32);
    const float inv = 1.0f / (s + 1e-8f);

    // cross-e reduce of value partials via LDS transpose
    #pragma unroll
    for (int jj = 0; jj < 8; ++jj)
        *(f32x4*)&red[lane * 36 + jj * 4] = acc4[jj];
    __syncthreads();
    f32x4 sum = {};
    #pragma unroll
    for (int ep = 0; ep < 8; ++ep) {
        const f32x4 p = *(const f32x4*)&red[((ep << 3) + h) * 36 + (e << 2)];
        sum[0] += p[0]; sum[1] += p[1]; sum[2] += p[2]; sum[3] += p[3];
    }
    ushort4 o;
    o.x = f2bf(sum[0] * inv);
    o.y = f2bf(sum[1] * inv);
    o.z = f2bf(sum[2] * inv);
    o.w = f2bf(sum[3] * inv);
    *(ushort4*)(ao + (size_t)q * CD + (h << 5) + (e << 2)) = o;

    if (deg > 0) {
        // m, inv are this lane's head state (head = lane&7 = i&7 below)
        if (deg <= 8) {
            if (lane < (deg << 3))
                simw[(size_t)lo * NH + lane] = fexp2(wval0 - m) * inv;
        } else if (deg <= 16) {
            simw[(size_t)lo * NH + lane] = fexp2(wval0 - m) * inv;
            if (lane < ((deg - 8) << 3))
                simw[(size_t)(lo + 8) * NH + lane] = fexp2(wval1 - m) * inv;
        } else {
            asm volatile("s_waitcnt vmcnt(0)" ::: "memory");   // drain sim stores
            for (int i = lane; i < deg * 8; i += 64) {
                size_t idx = (size_t)lo * NH + i;
                float v = simw[idx];
                simw[idx] = fexp2(v - m) * inv;
            }
        }
    }
}

// ---------------------------------------------------------------- launch
extern "C" void kernel_launch(void* const* d_in, const int* in_sizes, int n_in,
                              void* d_out, int out_size, void* d_ws, size_t ws_size,
                              hipStream_t stream) {
    const float* q    = (const float*)d_in[0];
    const float* k    = (const float*)d_in[1];
    const float* bias = (const float*)d_in[2];
    const float* lnw  = (const float*)d_in[3];
    const float* lnb  = (const float*)d_in[4];
    const float* wq   = (const float*)d_in[5];
    const float* bq   = (const float*)d_in[6];
    const float* wk   = (const float*)d_in[7];
    const float* bk   = (const float*)d_in[8];
    const float* wo   = (const float*)d_in[9];
    const float* bo   = (const float*)d_in[10];
    const int*   src  = (const int*)d_in[11];
    const int*   dst  = (const int*)d_in[12];

    float* out_m = (float*)d_out;                   // [QN][CD] fp32
    float* out_w = out_m + (size_t)QN * CD;         // [NE][NH] fp32 (weights)

    ushort* qn_b = (ushort*)d_ws;                   // [QN][CD]  LN(q) bf16 -> reused as attn_out
    ushort* qp_b = qn_b + (size_t)QN * CD;          // [QN][CD]  qp bf16
    ushort* kp_b = qp_b + (size_t)QN * CD;          // [KVN][CD] kp bf16
    ushort* wb   = kp_b + (size_t)KVN * CD;         // 3 x [256*256] bf16 weights
    int*    rowlo = (int*)(wb + 3 * 65536);         // [QN+1]

    // kb (k converted to bf16) lives in the out_m region: consumed by gemm2<0>,
    // and out_m is only written by the final gemm2<1>.
    ushort* kb = (ushort*)d_out;                    // [KVN][CD] bf16 (32 MB of 64)

    prep_k<<<dim3(LNB + 192 + RLB + LNB), dim3(256), 0, stream>>>(
        q, k, lnw, lnb, wq, wk, wo, dst, qn_b, kb, wb, rowlo);

    // z=0: qp = LN(q)@wq ; z=1: kp = kb@wk   (both bf16, identical blocks)
    gemm2_k<0, 8><<<dim3(64, 2, 2), dim3(512), 0, stream>>>(
        qn_b, kb, wb, wb + 65536, bq, bk, nullptr, qp_b, kp_b);

    edge_attn_k<<<dim3(QN), dim3(64), 0, stream>>>(
        qp_b, kp_b, bias, src, rowlo, qn_b /*ao*/, out_w);

    // out = attn_out@wo + bo + q
    gemm2_k<1, 4><<<dim3(128, 2, 1), dim3(512), 0, stream>>>(
        qn_b, qn_b, wb + 131072, wb + 131072, bo, bo, q, out_m, out_m);
}

// Round 7
// 175.380 us; speedup vs baseline: 1.2137x; 1.0027x over previous
//
#include <hip/hip_runtime.h>
#include <cmath>

#define QN    65536
#define KVN   65536
#define CD    256
#define NH    8
#define NE    524288
#define SCL   0.0625f      // 1/sqrt(256)
#define LNEPS 1e-5f
#define LOG2E 1.4426950408889634f

typedef __bf16 bf16x8 __attribute__((ext_vector_type(8)));
typedef float  f32x4  __attribute__((ext_vector_type(4)));

__device__ __forceinline__ float b2f(ushort u) {
    return __builtin_bit_cast(float, (unsigned)u << 16);
}
__device__ __forceinline__ float blo(unsigned u) {
    return __builtin_bit_cast(float, u << 16);
}
__device__ __forceinline__ float bhi(unsigned u) {
    return __builtin_bit_cast(float, u & 0xFFFF0000u);
}
__device__ __forceinline__ ushort f2bf(float f) {
    unsigned u = __builtin_bit_cast(unsigned, f);
    return (ushort)((u + 0x7FFFu + ((u >> 16) & 1u)) >> 16);   // RNE
}

#if __has_builtin(__builtin_amdgcn_exp2f)
__device__ __forceinline__ float fexp2(float x) { return __builtin_amdgcn_exp2f(x); }
#else
__device__ __forceinline__ float fexp2(float x) {
    float r; asm volatile("v_exp_f32 %0, %1" : "=v"(r) : "v"(x)); return r;
}
#endif

#define GLD16(g, l) __builtin_amdgcn_global_load_lds( \
    (const __attribute__((address_space(1))) unsigned int*)(const void*)(g), \
    (__attribute__((address_space(3))) unsigned int*)(void*)(l), 16, 0, 0)

// ---------------------------------------------------------------- fused prep:
// blk [0, LNB):          LN(q) -> bf16 qn           (4 rows/block)
// blk [LNB, LNB+192):    wq|wk|wo fp32 -> bf16      (1024 els/block)
// blk [.., +NE/256):     CSR row_lo fill
// blk [.., +LNB):        k fp32 -> bf16 kb          (4 rows/block)
#define LNB   (QN / 4)
#define RLB   (NE / 256)
__global__ __launch_bounds__(256) void prep_k(const float* __restrict__ q,
                                              const float* __restrict__ k,
                                              const float* __restrict__ lnw,
                                              const float* __restrict__ lnb,
                                              const float* __restrict__ wq,
                                              const float* __restrict__ wk,
                                              const float* __restrict__ wo,
                                              const int* __restrict__ dst,
                                              ushort* __restrict__ qn,
                                              ushort* __restrict__ kb,
                                              ushort* __restrict__ wb,
                                              int* __restrict__ row_lo) {
    const int blk = blockIdx.x;
    if (blk < LNB) {
        int row  = (blk << 2) + (threadIdx.x >> 6);
        int lane = threadIdx.x & 63;
        float4 v = *(const float4*)(q + (size_t)row * CD + (lane << 2));
        float s  = v.x + v.y + v.z + v.w;
        float s2 = v.x * v.x + v.y * v.y + v.z * v.z + v.w * v.w;
        #pragma unroll
        for (int m = 1; m < 64; m <<= 1) {
            s  += __shfl_xor(s, m);
            s2 += __shfl_xor(s2, m);
        }
        float mu   = s * (1.0f / CD);
        float rstd = rsqrtf(s2 * (1.0f / CD) - mu * mu + LNEPS);
        float4 w = *(const float4*)(lnw + (lane << 2));
        float4 b = *(const float4*)(lnb + (lane << 2));
        ushort4 o;
        o.x = f2bf((v.x - mu) * rstd * w.x + b.x);
        o.y = f2bf((v.y - mu) * rstd * w.y + b.y);
        o.z = f2bf((v.z - mu) * rstd * w.z + b.z);
        o.w = f2bf((v.w - mu) * rstd * w.w + b.w);
        *(ushort4*)(qn + (size_t)row * CD + (lane << 2)) = o;
    } else if (blk < LNB + 192) {
        int idx4 = ((blk - LNB) * 256 + threadIdx.x) * 4;   // 0 .. 3*65536
        int mat  = idx4 >> 16;
        int off  = idx4 & 65535;
        const float* src = (mat == 0) ? wq : (mat == 1) ? wk : wo;
        float4 v = *(const float4*)(src + off);
        ushort4 o;
        o.x = f2bf(v.x); o.y = f2bf(v.y); o.z = f2bf(v.z); o.w = f2bf(v.w);
        *(ushort4*)(wb + idx4) = o;
    } else if (blk < LNB + 192 + RLB) {
        int e = (blk - LNB - 192) * 256 + threadIdx.x;
        int d     = dst[e];
        int dprev = (e == 0) ? -1 : dst[e - 1];
        for (int qq = dprev + 1; qq <= d; ++qq) row_lo[qq] = e;
        if (e == NE - 1)
            for (int qq = d + 1; qq <= QN; ++qq) row_lo[qq] = NE;
    } else {
        int row  = ((blk - LNB - 192 - RLB) << 2) + (threadIdx.x >> 6);
        int lane = threadIdx.x & 63;
        float4 v = *(const float4*)(k + (size_t)row * CD + (lane << 2));
        ushort4 o;
        o.x = f2bf(v.x); o.y = f2bf(v.y); o.z = f2bf(v.z); o.w = f2bf(v.w);
        *(ushort4*)(kb + (size_t)row * CD + (lane << 2)) = o;
    }
}

// ---------------------------------------------------------------- persistent bf16 GEMM
// Proven R2 kernel, byte-identical. One block per CU (LDS 128 KB), 512 threads
// = 8 waves (2m x 4n), tile 128x128. B panel in LDS once; A via 8-slot GLD16
// ring, stage-ahead-6, counted vmcnt; one barrier per K-step; swapped-operand
// MFMA -> vectorized epilogue. EPI 0: bf16 out (E=8). EPI 1: f32 + resid (E=16).
template<int EPI, int NT>
__global__ __launch_bounds__(512) void gemm2_k(const ushort* __restrict__ A0,
                                               const ushort* __restrict__ A1,
                                               const ushort* __restrict__ B0,
                                               const ushort* __restrict__ B1,
                                               const float* __restrict__ bias0,
                                               const float* __restrict__ bias1,
                                               const float* __restrict__ resid,
                                               void* __restrict__ C0,
                                               void* __restrict__ C1) {
    const bool second = (blockIdx.z != 0);
    const ushort* Ap   = second ? A1 : A0;
    const ushort* B    = second ? B1 : B0;
    const float*  bias = second ? bias1 : bias0;
    void*         Cout = second ? C1 : C0;

    __shared__ __align__(16) ushort Bs[8][4096];   // 64 KB: full B panel, 8 k-slices
    __shared__ __align__(16) ushort As[8][4096];   // 64 KB: A ring, 8 slots

    const int t    = threadIdx.x;
    const int lane = t & 63;
    const int wid  = t >> 6;             // 0..7
    const int wm   = wid & 1;            // 2 wave-rows
    const int wn   = wid >> 1;           // 4 wave-cols
    const size_t bn  = (size_t)blockIdx.y * 128;
    size_t bm = (size_t)blockIdx.x * (NT * 128);

    const int sr = t >> 2;               // 0..127 staging row
    const int sc = (t & 3) * 8;          // staging col (8 elems = 16B)

    constexpr int E = (EPI == 0) ? 8 : 16;   // epilogue vmem instrs

    f32x4 acc[4][2] = {};
    f32x4 biasv[2];
    #pragma unroll
    for (int ni = 0; ni < 2; ++ni)
        biasv[ni] = *(const f32x4*)(bias + bn + wn * 32 + ni * 16 + ((lane >> 4) << 2));

    // ---- prologue: whole B panel + A slots 0..5
    #pragma unroll
    for (int s = 0; s < 8; ++s)
        GLD16(B + (bn + sr) * CD + (s << 5) + sc, &Bs[s][wid << 9]);
    #pragma unroll
    for (int s = 0; s < 6; ++s)
        GLD16(Ap + (bm + sr) * CD + (s << 5) + sc, &As[s][wid << 9]);
    asm volatile("" : "+v"(biasv[0]), "+v"(biasv[1]));

#define KSTEP(KT, VM, GUARD)                                                          \
  {                                                                                   \
    if (GUARD) {                                                                      \
      const ushort* ga_ = Ap + (bm + (((KT) >= 2) ? 128 : 0) + sr) * CD               \
                          + ((((KT) + 6) & 7) << 5) + sc;                             \
      GLD16(ga_, &As[((KT) + 6) & 7][wid << 9]);                                      \
    }                                                                                 \
    asm volatile("s_waitcnt vmcnt(%0) lgkmcnt(0)\n\ts_barrier" :: "i"(VM) : "memory");\
    {                                                                                 \
      const int kq_ = (lane >> 4) << 3;                                               \
      bf16x8 af_[4], bg_[2];                                                          \
      _Pragma("unroll")                                                               \
      for (int mi = 0; mi < 4; ++mi)                                                  \
        af_[mi] = *(const bf16x8*)&As[(KT) & 7][((wm * 64 + mi * 16 + (lane & 15)) << 5) + kq_]; \
      _Pragma("unroll")                                                               \
      for (int ni = 0; ni < 2; ++ni)                                                  \
        bg_[ni] = *(const bf16x8*)&Bs[(KT)][((wn * 32 + ni * 16 + (lane & 15)) << 5) + kq_];     \
      _Pragma("unroll")                                                               \
      for (int mi = 0; mi < 4; ++mi)                                                  \
        _Pragma("unroll")                                                             \
        for (int ni = 0; ni < 2; ++ni)                                                \
          acc[mi][ni] = __builtin_amdgcn_mfma_f32_16x16x32_bf16(bg_[ni], af_[mi], acc[mi][ni], 0, 0, 0); \
    }                                                                                 \
  }

#define EPILOG()                                                                      \
  {                                                                                   \
    _Pragma("unroll")                                                                 \
    for (int mi = 0; mi < 4; ++mi) {                                                  \
      const size_t row_ = bm + wm * 64 + mi * 16 + (lane & 15);                       \
      _Pragma("unroll")                                                               \
      for (int ni = 0; ni < 2; ++ni) {                                                \
        const size_t col_ = bn + wn * 32 + ni * 16 + ((lane >> 4) << 2);              \
        if (EPI == 0) {                                                               \
          ushort4 o_;                                                                 \
          o_.x = f2bf(acc[mi][ni][0] + biasv[ni][0]);                                 \
          o_.y = f2bf(acc[mi][ni][1] + biasv[ni][1]);                                 \
          o_.z = f2bf(acc[mi][ni][2] + biasv[ni][2]);                                 \
          o_.w = f2bf(acc[mi][ni][3] + biasv[ni][3]);                                 \
          *(ushort4*)((ushort*)Cout + row_ * CD + col_) = o_;                         \
        } else {                                                                      \
          f32x4 rs_ = *(const f32x4*)(resid + row_ * CD + col_);                      \
          f32x4 o_;                                                                   \
          o_[0] = acc[mi][ni][0] + biasv[ni][0] + rs_[0];                             \
          o_[1] = acc[mi][ni][1] + biasv[ni][1] + rs_[1];                             \
          o_[2] = acc[mi][ni][2] + biasv[ni][2] + rs_[2];                             \
          o_[3] = acc[mi][ni][3] + biasv[ni][3] + rs_[3];                             \
          *(f32x4*)((float*)Cout + row_ * CD + col_) = o_;                            \
        }                                                                             \
        acc[mi][ni] = (f32x4){0.f, 0.f, 0.f, 0.f};                                    \
      }                                                                               \
    }                                                                                 \
    asm volatile("" ::: "memory");                                                    \
  }

    // ---- tile 0
    KSTEP(0, 6, 1) KSTEP(1, 6, 1) KSTEP(2, 6, 1) KSTEP(3, 6, 1)
    KSTEP(4, 6, 1) KSTEP(5, 6, 1) KSTEP(6, 6, 1) KSTEP(7, 6, 1)
    EPILOG();
    bm += 128;

    // ---- middle tiles
    for (int tt = 1; tt < NT - 1; ++tt) {
        KSTEP(0, 6 + E, 1) KSTEP(1, 6 + E, 1) KSTEP(2, 6 + E, 1) KSTEP(3, 6 + E, 1)
        KSTEP(4, 6 + E, 1) KSTEP(5, 6 + E, 1) KSTEP(6, 6, 1)     KSTEP(7, 6, 1)
        EPILOG();
        bm += 128;
    }

    // ---- last tile
    KSTEP(0, 6 + E, 1) KSTEP(1, 6 + E, 1) KSTEP(2, 5 + E, 0) KSTEP(3, 4 + E, 0)
    KSTEP(4, 3 + E, 0) KSTEP(5, 2 + E, 0) KSTEP(6, 1, 0)     KSTEP(7, 0, 0)
    EPILOG();

#undef KSTEP
#undef EPILOG
}

// ---------------------------------------------------------------- edge attention
// v6: lane (e,h) owns its FINAL 4 output channels h*32+e*4..+3 across ALL 8
// edges of the chunk (R6 bug: v5 broadcast source-selected sub-blocks; the
// channel choice must be the RECEIVER's). Per edge the wave reads a contiguous
// 512 B (64 lanes x 8 B). Partial dot = 4 FMA/edge; one 3-round vector
// butterfly (shfl_xor 8/16/32 over 8 partials) gives EVERY lane all 8 sims of
// its head -> softmax fully local (no cross-lane softmax at all), and the
// value accumulation acc[c] += ex[ep]*ku[ep][c] is local and channel-correct.
// Zero LDS (R5 lesson), VGPR ~48.
__global__ __launch_bounds__(64) void edge_attn_k(const ushort* __restrict__ qp,
                                                  const ushort* __restrict__ kp,
                                                  const float* __restrict__ bias,
                                                  const int* __restrict__ src,
                                                  const int* __restrict__ row_lo,
                                                  ushort* __restrict__ ao,
                                                  float* __restrict__ simw) {
    const int q    = blockIdx.x;
    const int lane = threadIdx.x;
    const int e    = lane >> 3;          // output-channel-block slot 0..7
    const int h    = lane & 7;           // head
    const int lo = row_lo[q];
    const int hi = row_lo[q + 1];
    const int deg = hi - lo;
    const float SC2 = SCL * LOG2E;

    // own q channels h*32+e*4 .. +3 (2 uints = 4 bf16)
    const uint2 qv2 = *(const uint2*)(qp + (size_t)q * CD + (h << 5) + (e << 2));

    f32x4 acc = {0.f, 0.f, 0.f, 0.f};    // final channels h*32 + e*4 .. +3
    float m = -INFINITY, s = 0.f;
    float wval0 = -INFINITY, wval1 = -INFINITY;

    for (int base = lo; base < hi; base += 8) {
        // src for edges base..base+7 (lanes 0-7, guarded), bias own (coalesced)
        int sv = 0;
        if (lane < 8 && base + lane < hi) sv = src[base + lane];
        float bv = 0.f;
        if (lane < (hi - base) * 8) bv = bias[(size_t)base * NH + lane] * SC2;

        // per-edge 8-B slice of own channels (wave-uniform guard per edge)
        uint2 ku[8];
        #pragma unroll
        for (int ep = 0; ep < 8; ++ep) {
            ku[ep].x = 0u; ku[ep].y = 0u;
            if (base + ep < hi) {
                int sidx = __shfl(sv, ep);
                ku[ep] = *(const uint2*)(kp + (size_t)sidx * CD + (h << 5) + (e << 2));
            }
        }
        // partial dots over own 4 channels
        float p[8];
        #pragma unroll
        for (int ep = 0; ep < 8; ++ep) {
            float d;
            d = blo(qv2.x) * blo(ku[ep].x);
            d = fmaf(bhi(qv2.x), bhi(ku[ep].x), d);
            d = fmaf(blo(qv2.y), blo(ku[ep].y), d);
            d = fmaf(bhi(qv2.y), bhi(ku[ep].y), d);
            p[ep] = d;
        }
        // butterfly over e-lanes (h preserved): all lanes get full 32-ch dots
        #pragma unroll
        for (int r = 8; r <= 32; r <<= 1) {
            #pragma unroll
            for (int ep = 0; ep < 8; ++ep)
                p[ep] += __shfl_xor(p[ep], r);
        }
        // + bias (bpermute from the coalesced bv); inactive -> -inf
        float sims[8];
        #pragma unroll
        for (int ep = 0; ep < 8; ++ep) {
            float bvp = __shfl(bv, (ep << 3) + h);
            sims[ep] = (base + ep < hi) ? fmaf(p[ep], SC2, bvp) : -INFINITY;
        }
        // local per-head softmax (identical across the 8 e-lanes of a head)
        float cmax = sims[0];
        #pragma unroll
        for (int ep = 1; ep < 8; ++ep) cmax = fmaxf(cmax, sims[ep]);
        const float mnew  = fmaxf(m, cmax);
        const float scale = fexp2(m - mnew);     // first chunk: exp2(-inf)=0
        acc[0] *= scale; acc[1] *= scale; acc[2] *= scale; acc[3] *= scale;
        float esum = 0.f;
        #pragma unroll
        for (int ep = 0; ep < 8; ++ep) {
            const float ex = fexp2(sims[ep] - mnew);   // inactive: 0
            esum += ex;
            acc[0] = fmaf(ex, blo(ku[ep].x), acc[0]);
            acc[1] = fmaf(ex, bhi(ku[ep].x), acc[1]);
            acc[2] = fmaf(ex, blo(ku[ep].y), acc[2]);
            acc[3] = fmaf(ex, bhi(ku[ep].y), acc[3]);
        }
        s = s * scale + esum;
        m = mnew;

        // own-edge sim (edge base+e, head h) via cndmask tree
        float ta = (e & 1) ? sims[1] : sims[0];
        float tb = (e & 1) ? sims[3] : sims[2];
        float tc = (e & 1) ? sims[5] : sims[4];
        float td = (e & 1) ? sims[7] : sims[6];
        float te = (e & 2) ? tb : ta;
        float tf = (e & 2) ? td : tc;
        float own = (e & 4) ? tf : te;
        if (deg <= 16) {
            if (base == lo) wval0 = own; else wval1 = own;
        } else if (base + e < hi) {
            simw[(size_t)base * NH + lane] = own;   // raw log2 sims staged
        }
    }

    // s, m are full per-head values (identical across e-lanes of the head)
    const float inv = 1.0f / (s + 1e-8f);

    ushort4 o;
    o.x = f2bf(acc[0] * inv);
    o.y = f2bf(acc[1] * inv);
    o.z = f2bf(acc[2] * inv);
    o.w = f2bf(acc[3] * inv);
    *(ushort4*)(ao + (size_t)q * CD + (h << 5) + (e << 2)) = o;

    if (deg > 0) {
        if (deg <= 8) {
            if (lane < (deg << 3))
                simw[(size_t)lo * NH + lane] = fexp2(wval0 - m) * inv;
        } else if (deg <= 16) {
            simw[(size_t)lo * NH + lane] = fexp2(wval0 - m) * inv;
            if (lane < ((deg - 8) << 3))
                simw[(size_t)(lo + 8) * NH + lane] = fexp2(wval1 - m) * inv;
        } else {
            asm volatile("s_waitcnt vmcnt(0)" ::: "memory");   // drain sim stores
            for (int i = lane; i < deg * 8; i += 64) {
                size_t idx = (size_t)lo * NH + i;   // head = i&7 = lane&7 = h
                float v = simw[idx];
                simw[idx] = fexp2(v - m) * inv;
            }
        }
    }
}

// ---------------------------------------------------------------- launch
extern "C" void kernel_launch(void* const* d_in, const int* in_sizes, int n_in,
                              void* d_out, int out_size, void* d_ws, size_t ws_size,
                              hipStream_t stream) {
    const float* q    = (const float*)d_in[0];
    const float* k    = (const float*)d_in[1];
    const float* bias = (const float*)d_in[2];
    const float* lnw  = (const float*)d_in[3];
    const float* lnb  = (const float*)d_in[4];
    const float* wq   = (const float*)d_in[5];
    const float* bq   = (const float*)d_in[6];
    const float* wk   = (const float*)d_in[7];
    const float* bk   = (const float*)d_in[8];
    const float* wo   = (const float*)d_in[9];
    const float* bo   = (const float*)d_in[10];
    const int*   src  = (const int*)d_in[11];
    const int*   dst  = (const int*)d_in[12];

    float* out_m = (float*)d_out;                   // [QN][CD] fp32
    float* out_w = out_m + (size_t)QN * CD;         // [NE][NH] fp32 (weights)

    ushort* qn_b = (ushort*)d_ws;                   // [QN][CD]  LN(q) bf16 -> reused as attn_out
    ushort* qp_b = qn_b + (size_t)QN * CD;          // [QN][CD]  qp bf16
    ushort* kp_b = qp_b + (size_t)QN * CD;          // [KVN][CD] kp bf16
    ushort* wb   = kp_b + (size_t)KVN * CD;         // 3 x [256*256] bf16 weights
    int*    rowlo = (int*)(wb + 3 * 65536);         // [QN+1]

    // kb (k converted to bf16) lives in the out_m region: consumed by gemm2<0>,
    // and out_m is only written by the final gemm2<1>.
    ushort* kb = (ushort*)d_out;                    // [KVN][CD] bf16 (32 MB of 64)

    prep_k<<<dim3(LNB + 192 + RLB + LNB), dim3(256), 0, stream>>>(
        q, k, lnw, lnb, wq, wk, wo, dst, qn_b, kb, wb, rowlo);

    // z=0: qp = LN(q)@wq ; z=1: kp = kb@wk   (both bf16, identical blocks)
    gemm2_k<0, 8><<<dim3(64, 2, 2), dim3(512), 0, stream>>>(
        qn_b, kb, wb, wb + 65536, bq, bk, nullptr, qp_b, kp_b);

    edge_attn_k<<<dim3(QN), dim3(64), 0, stream>>>(
        qp_b, kp_b, bias, src, rowlo, qn_b /*ao*/, out_w);

    // out = attn_out@wo + bo + q
    gemm2_k<1, 4><<<dim3(128, 2, 1), dim3(512), 0, stream>>>(
        qn_b, qn_b, wb + 131072, wb + 131072, bo, bo, q, out_m, out_m);
}